// Round 1
// baseline (111.407 us; speedup 1.0000x reference)
//
#include <hip/hip_runtime.h>
#include <hip/hip_bf16.h>

// Problem constants (from reference): B=256, N=64, A=16, D=256
#define BB 256
#define NN 64
#define AA 16
#define DD 256
#define WCOLS (DD + AA * NN * NN)   // 65792, W row stride
#define NK (NN * NN)                // 4096 adj entries per batch row

// ---------------------------------------------------------------------------
// Kernel 1: logits -> mask -> argmax -> log_softmax -> actions + logp
// One block per batch row b; 256 threads cooperate on 16 dot products.
// logits[b,oa] = sum_d x[b,d]*W[oa,d]
//              + sum_k adj[b,k]*fw[k%64]*W[oa, 256 + 16*k]   (only a==0 cols)
//              + bias[oa]
// ---------------------------------------------------------------------------
__global__ __launch_bounds__(256) void actg_logits_kernel(
    const float* __restrict__ x, const int* __restrict__ adj,
    const float* __restrict__ avail, const float* __restrict__ fw,
    const float* __restrict__ W, const float* __restrict__ bias,
    float* __restrict__ out_actions, float* __restrict__ out_logp)
{
    const int b = blockIdx.x;
    const int t = threadIdx.x;

    __shared__ float s_fw[NN];
    __shared__ float s_part[4][AA];
    __shared__ float s_logits[AA];

    if (t < NN) s_fw[t] = fw[t];
    __syncthreads();

    float acc[AA];
#pragma unroll
    for (int a = 0; a < AA; ++a) acc[a] = 0.f;

    // --- adj (father_flat) contribution: k = it*256 + t -------------------
    const int* adjb = adj + b * NK;
    for (int it = 0; it < NK / 256; ++it) {
        const int k = it * 256 + t;
        const int av = adjb[k];
        if (av) {                       // ~75% zeros -> skip 16 W loads
            const float val = s_fw[k & (NN - 1)];
            const float* wp = W + DD + k * AA;   // column 256 + 16*k, row a
#pragma unroll
            for (int a = 0; a < AA; ++a)
                acc[a] += val * wp[a * WCOLS];
        }
    }

    // --- x contribution: d = t -------------------------------------------
    {
        const float xv = x[b * DD + t];
        const float* wp = W + t;
#pragma unroll
        for (int a = 0; a < AA; ++a)
            acc[a] += xv * wp[a * WCOLS];
    }

    // --- wave (64-lane) shuffle reduce, then cross-wave via LDS -----------
#pragma unroll
    for (int a = 0; a < AA; ++a) {
        float v = acc[a];
#pragma unroll
        for (int off = 32; off > 0; off >>= 1)
            v += __shfl_down(v, off, 64);
        acc[a] = v;
    }
    const int wave = t >> 6;
    if ((t & 63) == 0) {
#pragma unroll
        for (int a = 0; a < AA; ++a) s_part[wave][a] = acc[a];
    }
    __syncthreads();

    if (t < AA) {
        float v = s_part[0][t] + s_part[1][t] + s_part[2][t] + s_part[3][t]
                + bias[t];
        v = (avail[b * AA + t] > 0.f) ? v : -1e10f;
        s_logits[t] = v;
    }
    __syncthreads();

    if (t == 0) {
        float m = s_logits[0];
        int am = 0;
#pragma unroll
        for (int a = 1; a < AA; ++a) {
            const float v = s_logits[a];
            if (v > m) { m = v; am = a; }   // strict > == first-occurrence argmax
        }
        float s = 0.f;
#pragma unroll
        for (int a = 0; a < AA; ++a) s += expf(s_logits[a] - m);
        out_actions[b] = (float)am;
        out_logp[b]    = -logf(s);          // logp_all[argmax] = m - m - log(s)
    }
}

// ---------------------------------------------------------------------------
// Kernel 2: materialize father_flat [B, N*N*A] = 16,777,216 floats (64 MB).
// out[b, k, a] = (a==0) ? adj[b,k]*fw[k%64] : 0
// One float4 per thread, consecutive lanes -> consecutive 16B: fully coalesced.
// g in [0, B*NK*4); bk = g>>2 selects (b,k); a4 = g&3 selects the 4-float group.
// ---------------------------------------------------------------------------
__global__ __launch_bounds__(256) void actg_father_kernel(
    const int* __restrict__ adj, const float* __restrict__ fw,
    float4* __restrict__ out)
{
    const int g  = blockIdx.x * blockDim.x + threadIdx.x;   // [0, 4194304)
    const int bk = g >> 2;
    const int a4 = g & 3;
    // Load unconditionally (broadcast across 4 lanes, coalesced dwords).
    const float av = (float)adj[bk];
    const float v  = av * fw[bk & (NN - 1)];
    const float val = (a4 == 0) ? v : 0.f;
    out[g] = make_float4(val, 0.f, 0.f, 0.f);
}

// ---------------------------------------------------------------------------
extern "C" void kernel_launch(void* const* d_in, const int* in_sizes, int n_in,
                              void* d_out, int out_size, void* d_ws, size_t ws_size,
                              hipStream_t stream) {
    const float* x     = (const float*)d_in[0];   // [B, D]
    const int*   adj   = (const int*)  d_in[1];   // [B, N, N]
    const float* avail = (const float*)d_in[2];   // [B, A]
    const float* fw    = (const float*)d_in[3];   // [N]
    const float* W     = (const float*)d_in[4];   // [A, D + A*N*N]
    const float* bias  = (const float*)d_in[5];   // [A]

    float* out = (float*)d_out;
    // Output layout (concat flat, return order):
    //   actions [B,1] -> out[0..255]
    //   logp    [B,1] -> out[256..511]
    //   father  [B, N*N*A] -> out[512 .. 512+16777216)
    float*  out_actions = out;
    float*  out_logp    = out + BB;
    float4* out_father  = (float4*)(out + 2 * BB);   // 2048-byte offset, aligned

    actg_logits_kernel<<<BB, 256, 0, stream>>>(
        x, adj, avail, fw, W, bias, out_actions, out_logp);

    const int total_f4 = BB * NK * (AA / 4);         // 4,194,304
    actg_father_kernel<<<total_f4 / 256, 256, 0, stream>>>(
        adj, fw, out_father);
}

// Round 2
// 101.366 us; speedup vs baseline: 1.0991x; 1.0991x over previous
//
#include <hip/hip_runtime.h>
#include <hip/hip_bf16.h>

// Problem constants (from reference): B=256, N=64, A=16, D=256
#define BB 256
#define NN 64
#define AA 16
#define DD 256
#define WCOLS (DD + AA * NN * NN)   // 65792, W row stride
#define NK (NN * NN)                // 4096 adj entries per batch row

// ---------------------------------------------------------------------------
// Stage A: compact the only-used W columns (a_sub==0 -> col 256+16k) into a
// dense Wc[k][a] table (4096 x 16 floats = 256 KB) in d_ws. One-time gather;
// afterwards everything reads Wc L2-resident and contiguous.
// t = a*4096 + k: consecutive lanes read consecutive-k (stride 64 B) from one
// contiguous 256 KB row region -> full lines are fetched once, all used.
// ---------------------------------------------------------------------------
__global__ __launch_bounds__(256) void actg_compact_kernel(
    const float* __restrict__ W, float* __restrict__ Wc)
{
    const int t = blockIdx.x * 256 + threadIdx.x;   // [0, 65536)
    const int a = t >> 12;                          // 0..15
    const int k = t & (NK - 1);                     // 0..4095
    Wc[k * AA + a] = W[a * WCOLS + DD + k * AA];
}

// ---------------------------------------------------------------------------
// Stage B: logits -> mask -> argmax -> log_softmax. One block per batch row.
// adj contribution uses the dense Wc (4 x float4 per active k, L2-resident).
// ---------------------------------------------------------------------------
__global__ __launch_bounds__(256) void actg_logits_kernel(
    const float* __restrict__ x, const int* __restrict__ adj,
    const float* __restrict__ avail, const float* __restrict__ fw,
    const float* __restrict__ W, const float* __restrict__ bias,
    const float* __restrict__ Wc,
    float* __restrict__ out_actions, float* __restrict__ out_logp)
{
    const int b = blockIdx.x;
    const int t = threadIdx.x;

    __shared__ float s_fw[NN];
    __shared__ float s_part[4][AA];
    __shared__ float s_logits[AA];

    if (t < NN) s_fw[t] = fw[t];
    __syncthreads();

    float acc[AA];
#pragma unroll
    for (int a = 0; a < AA; ++a) acc[a] = 0.f;

    const int4*   adjb4 = (const int4*)(adj + b * NK);
    const float4* Wc4   = (const float4*)Wc;

#define PROC(AVQ, KQ)                                              \
    if (AVQ) {                                                     \
        const float  val = s_fw[(KQ) & (NN - 1)];                  \
        const float4 w0  = Wc4[(KQ) * 4 + 0];                      \
        const float4 w1  = Wc4[(KQ) * 4 + 1];                      \
        const float4 w2  = Wc4[(KQ) * 4 + 2];                      \
        const float4 w3  = Wc4[(KQ) * 4 + 3];                      \
        acc[0]  += val * w0.x;  acc[1]  += val * w0.y;             \
        acc[2]  += val * w0.z;  acc[3]  += val * w0.w;             \
        acc[4]  += val * w1.x;  acc[5]  += val * w1.y;             \
        acc[6]  += val * w1.z;  acc[7]  += val * w1.w;             \
        acc[8]  += val * w2.x;  acc[9]  += val * w2.y;             \
        acc[10] += val * w2.z;  acc[11] += val * w2.w;             \
        acc[12] += val * w3.x;  acc[13] += val * w3.y;             \
        acc[14] += val * w3.z;  acc[15] += val * w3.w;             \
    }

#pragma unroll
    for (int it = 0; it < NK / (256 * 4); ++it) {   // 4 iterations
        const int4 av = adjb4[it * 256 + t];
        const int  k0 = (it * 256 + t) * 4;
        PROC(av.x, k0 + 0)
        PROC(av.y, k0 + 1)
        PROC(av.z, k0 + 2)
        PROC(av.w, k0 + 3)
    }
#undef PROC

    // --- x contribution: d = t (lanes coalesced per a) --------------------
    {
        const float xv = x[b * DD + t];
        const float* wp = W + t;
#pragma unroll
        for (int a = 0; a < AA; ++a)
            acc[a] += xv * wp[a * WCOLS];
    }

    // --- wave (64-lane) shuffle reduce, then cross-wave via LDS -----------
#pragma unroll
    for (int a = 0; a < AA; ++a) {
        float v = acc[a];
#pragma unroll
        for (int off = 32; off > 0; off >>= 1)
            v += __shfl_down(v, off, 64);
        acc[a] = v;
    }
    const int wave = t >> 6;
    if ((t & 63) == 0) {
#pragma unroll
        for (int a = 0; a < AA; ++a) s_part[wave][a] = acc[a];
    }
    __syncthreads();

    if (t < AA) {
        float v = s_part[0][t] + s_part[1][t] + s_part[2][t] + s_part[3][t]
                + bias[t];
        v = (avail[b * AA + t] > 0.f) ? v : -1e10f;
        s_logits[t] = v;
    }
    __syncthreads();

    if (t == 0) {
        float m = s_logits[0];
        int am = 0;
#pragma unroll
        for (int a = 1; a < AA; ++a) {
            const float v = s_logits[a];
            if (v > m) { m = v; am = a; }   // strict > == first-occurrence argmax
        }
        float s = 0.f;
#pragma unroll
        for (int a = 0; a < AA; ++a) s += expf(s_logits[a] - m);
        out_actions[b] = (float)am;
        out_logp[b]    = -logf(s);          // logp_all[argmax] = m - m - log(s)
    }
}

// ---------------------------------------------------------------------------
// Father kernel: materialize father_flat [B, N*N*A] = 64 MB.
// out[b, k, a] = (a==0) ? adj[b,k]*fw[k%64] : 0
// One float4 per thread, consecutive lanes -> consecutive 16 B: coalesced.
// ---------------------------------------------------------------------------
__global__ __launch_bounds__(256) void actg_father_kernel(
    const int* __restrict__ adj, const float* __restrict__ fw,
    float4* __restrict__ out)
{
    const int g  = blockIdx.x * blockDim.x + threadIdx.x;   // [0, 4194304)
    const int bk = g >> 2;
    const int a4 = g & 3;
    const float av = (float)adj[bk];
    const float v  = av * fw[bk & (NN - 1)];
    const float val = (a4 == 0) ? v : 0.f;
    out[g] = make_float4(val, 0.f, 0.f, 0.f);
}

// ---------------------------------------------------------------------------
extern "C" void kernel_launch(void* const* d_in, const int* in_sizes, int n_in,
                              void* d_out, int out_size, void* d_ws, size_t ws_size,
                              hipStream_t stream) {
    const float* x     = (const float*)d_in[0];   // [B, D]
    const int*   adj   = (const int*)  d_in[1];   // [B, N, N]
    const float* avail = (const float*)d_in[2];   // [B, A]
    const float* fw    = (const float*)d_in[3];   // [N]
    const float* W     = (const float*)d_in[4];   // [A, D + A*N*N]
    const float* bias  = (const float*)d_in[5];   // [A]

    float* out = (float*)d_out;
    // Output layout (concat flat, return order):
    //   actions [B,1] -> out[0..255]
    //   logp    [B,1] -> out[256..511]
    //   father  [B, N*N*A] -> out[512 ..)
    float*  out_actions = out;
    float*  out_logp    = out + BB;
    float4* out_father  = (float4*)(out + 2 * BB);

    float* Wc = (float*)d_ws;                      // 4096*16 floats = 256 KB

    actg_compact_kernel<<<NK * AA / 256, 256, 0, stream>>>(W, Wc);

    actg_logits_kernel<<<BB, 256, 0, stream>>>(
        x, adj, avail, fw, W, bias, Wc, out_actions, out_logp);

    const int total_f4 = BB * NK * (AA / 4);       // 4,194,304
    actg_father_kernel<<<total_f4 / 256, 256, 0, stream>>>(
        adj, fw, out_father);
}

// Round 3
// 96.396 us; speedup vs baseline: 1.1557x; 1.0516x over previous
//
#include <hip/hip_runtime.h>
#include <hip/hip_bf16.h>

// Problem constants (from reference): B=256, N=64, A=16, D=256
#define BB 256
#define NN 64
#define AA 16
#define DD 256
#define WCOLS (DD + AA * NN * NN)   // 65792, W row stride
#define NK (NN * NN)                // 4096 adj entries per batch row

// ---------------------------------------------------------------------------
// D1: compact the only-used W columns (a_sub==0 -> col 256+16k) into a dense
// Wc[k][a] table (4096 x 16 floats = 256 KB) in d_ws.
// t -> k = t>>4, a = t&15: stores fully coalesced (consecutive lanes write
// consecutive floats of Wc); loads fetch all of W once (~4 MB, ~0.7 us).
// ---------------------------------------------------------------------------
__global__ __launch_bounds__(256) void actg_compact_kernel(
    const float* __restrict__ W, float* __restrict__ Wc)
{
    const int t = blockIdx.x * 256 + threadIdx.x;   // [0, 65536)
    const int k = t >> 4;                           // 0..4095
    const int a = t & (AA - 1);                     // 0..15
    Wc[k * AA + a] = W[a * WCOLS + DD + k * AA];
}

// ---------------------------------------------------------------------------
// D2: fused. Blocks [0,256): logits/argmax/logsoftmax (one block per batch,
// starts first so it hides under the father traffic). Blocks [256, 16640):
// father_flat materialization, 64 MB coalesced float4 stores.
// ---------------------------------------------------------------------------
__global__ __launch_bounds__(256) void actg_main_kernel(
    const float* __restrict__ x, const int* __restrict__ adj,
    const float* __restrict__ avail, const float* __restrict__ fw,
    const float* __restrict__ W, const float* __restrict__ bias,
    const float* __restrict__ Wc,
    float* __restrict__ out_actions, float* __restrict__ out_logp,
    float4* __restrict__ out_father)
{
    const int t = threadIdx.x;

    if (blockIdx.x >= BB) {
        // ----------------- father path -----------------
        const int g  = (blockIdx.x - BB) * 256 + t;     // [0, 4194304)
        const int bk = g >> 2;
        const int a4 = g & 3;
        const float av  = (float)adj[bk];
        const float v   = av * fw[bk & (NN - 1)];
        const float val = (a4 == 0) ? v : 0.f;
        out_father[g] = make_float4(val, 0.f, 0.f, 0.f);
        return;
    }

    // ----------------- logits path -----------------
    const int b = blockIdx.x;

    __shared__ float s_fw[NN];
    __shared__ float s_part[4][AA];
    __shared__ float s_logits[AA];

    if (t < NN) s_fw[t] = fw[t];
    __syncthreads();

    float acc[AA];
#pragma unroll
    for (int a = 0; a < AA; ++a) acc[a] = 0.f;

    const int4*   adjb4 = (const int4*)(adj + b * NK);
    const float4* Wc4   = (const float4*)Wc;

#define PROC(AVQ, KQ)                                              \
    if (AVQ) {                                                     \
        const float  val = s_fw[(KQ) & (NN - 1)];                  \
        const float4 w0  = Wc4[(KQ) * 4 + 0];                      \
        const float4 w1  = Wc4[(KQ) * 4 + 1];                      \
        const float4 w2  = Wc4[(KQ) * 4 + 2];                      \
        const float4 w3  = Wc4[(KQ) * 4 + 3];                      \
        acc[0]  += val * w0.x;  acc[1]  += val * w0.y;             \
        acc[2]  += val * w0.z;  acc[3]  += val * w0.w;             \
        acc[4]  += val * w1.x;  acc[5]  += val * w1.y;             \
        acc[6]  += val * w1.z;  acc[7]  += val * w1.w;             \
        acc[8]  += val * w2.x;  acc[9]  += val * w2.y;             \
        acc[10] += val * w2.z;  acc[11] += val * w2.w;             \
        acc[12] += val * w3.x;  acc[13] += val * w3.y;             \
        acc[14] += val * w3.z;  acc[15] += val * w3.w;             \
    }

#pragma unroll
    for (int it = 0; it < NK / (256 * 4); ++it) {   // 4 iterations
        const int4 av = adjb4[it * 256 + t];
        const int  k0 = (it * 256 + t) * 4;
        PROC(av.x, k0 + 0)
        PROC(av.y, k0 + 1)
        PROC(av.z, k0 + 2)
        PROC(av.w, k0 + 3)
    }
#undef PROC

    // x contribution: d = t (lanes coalesced per a)
    {
        const float xv = x[b * DD + t];
        const float* wp = W + t;
#pragma unroll
        for (int a = 0; a < AA; ++a)
            acc[a] += xv * wp[a * WCOLS];
    }

    // wave (64-lane) shuffle reduce, then cross-wave via LDS
#pragma unroll
    for (int a = 0; a < AA; ++a) {
        float v = acc[a];
#pragma unroll
        for (int off = 32; off > 0; off >>= 1)
            v += __shfl_down(v, off, 64);
        acc[a] = v;
    }
    const int wave = t >> 6;
    if ((t & 63) == 0) {
#pragma unroll
        for (int a = 0; a < AA; ++a) s_part[wave][a] = acc[a];
    }
    __syncthreads();

    if (t < AA) {
        float v = s_part[0][t] + s_part[1][t] + s_part[2][t] + s_part[3][t]
                + bias[t];
        v = (avail[b * AA + t] > 0.f) ? v : -1e10f;
        s_logits[t] = v;
    }
    __syncthreads();

    if (t == 0) {
        float m = s_logits[0];
        int am = 0;
#pragma unroll
        for (int a = 1; a < AA; ++a) {
            const float v = s_logits[a];
            if (v > m) { m = v; am = a; }   // strict > == first-occurrence argmax
        }
        float s = 0.f;
#pragma unroll
        for (int a = 0; a < AA; ++a) s += expf(s_logits[a] - m);
        out_actions[b] = (float)am;
        out_logp[b]    = -logf(s);          // logp_all[argmax] = m - m - log(s)
    }
}

// ---------------------------------------------------------------------------
extern "C" void kernel_launch(void* const* d_in, const int* in_sizes, int n_in,
                              void* d_out, int out_size, void* d_ws, size_t ws_size,
                              hipStream_t stream) {
    const float* x     = (const float*)d_in[0];   // [B, D]
    const int*   adj   = (const int*)  d_in[1];   // [B, N, N]
    const float* avail = (const float*)d_in[2];   // [B, A]
    const float* fw    = (const float*)d_in[3];   // [N]
    const float* W     = (const float*)d_in[4];   // [A, D + A*N*N]
    const float* bias  = (const float*)d_in[5];   // [A]

    float* out = (float*)d_out;
    // Output layout (concat flat, return order):
    //   actions [B,1] -> out[0..255]
    //   logp    [B,1] -> out[256..511]
    //   father  [B, N*N*A] -> out[512 ..)
    float*  out_actions = out;
    float*  out_logp    = out + BB;
    float4* out_father  = (float4*)(out + 2 * BB);

    float* Wc = (float*)d_ws;                      // 4096*16 floats = 256 KB

    actg_compact_kernel<<<NK * AA / 256, 256, 0, stream>>>(W, Wc);

    const int father_blocks = BB * NK * (AA / 4) / 256;   // 16384
    actg_main_kernel<<<BB + father_blocks, 256, 0, stream>>>(
        x, adj, avail, fw, W, bias, Wc, out_actions, out_logp, out_father);
}